// Round 6
// baseline (424.792 us; speedup 1.0000x reference)
//
#include <hip/hip_runtime.h>
#include <float.h>

#define NBATCH 32
#define NBDP 16                    /* DP blocks: 2 batches per block, independent sync domains */
#define NBCE 32
#define L 128
#define NT 1024
#define R 132                      /* row stride (dwords) */
#define SQ_SIZE (L * R + 8)
#define LOGMIN -87.49823f          /* ln(1e-38) */

// ---- mask dtype runtime detection (element [0] is guaranteed true: lens >= 64) ----
__device__ __forceinline__ int mask_mode(const void* p) {
    unsigned int v = ((const unsigned int*)p)[0];
    if (v == 1u) return 1;            // int32 0/1 storage
    if (v == 0x3F800000u) return 2;   // float32 storage
    return 0;                         // byte storage
}
__device__ __forceinline__ bool mask_at(const void* p, int mode, int idx) {
    if (mode == 1) return ((const int*)p)[idx] != 0;
    if (mode == 2) return ((const float*)p)[idx] != 0.0f;
    return ((const unsigned char*)p)[idx] != 0;
}

__device__ __forceinline__ float lse2(float a, float b) {
    return fmaxf(a, b) + log1pf(__expf(-fabsf(a - b)));
}

// ---- DPP butterfly reduce within aligned subgroups of 8 lanes ----
template<int C>
__device__ __forceinline__ float dppf(float x) {
    return __int_as_float(__builtin_amdgcn_mov_dpp(__float_as_int(x), C, 0xF, 0xF, true));
}
__device__ __forceinline__ float bfly_max8(float x) {
    x = fmaxf(x, dppf<0xB1>(x));   // lane^1
    x = fmaxf(x, dppf<0x4E>(x));   // lane^2
    x = fmaxf(x, dppf<0x141>(x));  // ^7 within 8
    return x;
}
__device__ __forceinline__ float bfly_add8(float x) {
    x += dppf<0xB1>(x);
    x += dppf<0x4E>(x);
    x += dppf<0x141>(x);
    return x;
}

// ---- per-half 8-wave spin barrier (LDS counter, monotone target) ----
__device__ __forceinline__ void half_barrier(int* cnt, int target) {
    __builtin_amdgcn_fence(__ATOMIC_RELEASE, "workgroup");   // drain this wave's ds_writes
    if ((threadIdx.x & 63) == 0) atomicAdd(cnt, 1);
    if (__hip_atomic_load(cnt, __ATOMIC_RELAXED, __HIP_MEMORY_SCOPE_WORKGROUP) < target) {
        do {
            __builtin_amdgcn_s_sleep(1);
        } while (__hip_atomic_load(cnt, __ATOMIC_RELAXED, __HIP_MEMORY_SCOPE_WORKGROUP) < target);
    }
    __builtin_amdgcn_fence(__ATOMIC_ACQUIRE, "workgroup");
}

// ---- term loader: term t = sub + 8*m; p1 contiguous [t], p2 strided [t*R] ----
// masked lanes -> -FLT_MAX (later exp -> exact 0). Overreads masked, stay in LDS.
template<int NUMAX>
__device__ __forceinline__ void load_rc(float* v, int sub, int nterm,
                                        const float* p1, const float* p2, float& mloc) {
    p1 += sub; p2 += sub * R;
#pragma unroll
    for (int m = 0; m < NUMAX; m += 2) {
        if (m * 8 >= nterm) break;
        const int o0 = m * 8, o1 = o0 + 8;
        float a0 = p1[o0] + p2[o0 * R];
        float a1 = p1[o1] + p2[o1 * R];
        a0 = (sub + o0 < nterm) ? a0 : -FLT_MAX;
        a1 = (sub + o1 < nterm) ? a1 : -FLT_MAX;
        v[m] = a0; v[m + 1] = a1;
        mloc = fmaxf(mloc, fmaxf(a0, a1));
    }
}
template<int NUMAX>
__device__ __forceinline__ void sum_exp8(const float* v, int nterm, float M, float& s) {
#pragma unroll
    for (int m = 0; m < NUMAX; m += 2) {
        if (m * 8 >= nterm) break;
        s += __expf(v[m] - M) + __expf(v[m + 1] - M);
    }
}

// ---- inside cell: alpha[i,j] = sc + LSE_k( alpha[i,k] + alpha[k+1,j] ), k in [i,j) ----
template<int NU>
__device__ __forceinline__ void inside_cell(float* SQm, int i, int w, int sub) {
    const int j = i + w;
    float v[NU]; float mloc = -FLT_MAX;
    load_rc<NU>(v, sub, w, &SQm[i * R + i], &SQm[(i + 1) * R + j], mloc);
    float M = bfly_max8(mloc);
    float s = 0.0f;
    sum_exp8<NU>(v, w, M, s);
    float S = bfly_add8(s);
    if (sub == 0) SQm[i * R + j] += M + __logf(S);   // slot held sc
}

// ---- outside cell: gamma[i,j] = sc + LSE( U: k>j gamma[i,k]+alpha[j+1,k] ;
//                                           V: k<i gamma[k,j]+alpha[k,i-1] ) ----
template<int NU, int NV>
__device__ __forceinline__ float outside_cell(float* SQm, int i, int j, int n, int sub, bool store) {
    float v1[NU], v2[NV]; float mloc = -FLT_MAX;
    const int ntU = n - 1 - j;
    load_rc<NU>(v1, sub, ntU, &SQm[(j + 1) * R + (j + 1)], &SQm[(j + 1) * R + i], mloc);
    const float* p2v = &SQm[(i >= 1 ? i - 1 : 0)];
    load_rc<NV>(v2, sub, i, &SQm[j * R], p2v, mloc);
    float M = bfly_max8(mloc);
    float s = 0.0f;
    sum_exp8<NU>(v1, ntU, M, s);
    sum_exp8<NV>(v2, i, M, s);
    float S = bfly_add8(s);
    float out = 0.0f;
    if (sub == 0) {
        out = M + __logf(S);
        if (store) SQm[j * R + i] += out;   // lower slot held sc
    }
    return out;
}

// ================= fused kernel: blocks [0,NBDP) = 2-batch DP; [NBDP,NBDP+NBCE) = BCE =================
__global__ __launch_bounds__(NT, 1) void tree_dp_kernel(
    const float* __restrict__ logits,   // [B,L,L,2]
    const int*   __restrict__ spans_ind,// [B,L,L]
    const void*  __restrict__ maskspan, // [B,L,L] bool
    const float* __restrict__ ph, const float* __restrict__ pt,
    const int* __restrict__ ph_ind, const int* __restrict__ pt_ind,
    const void* __restrict__ maskarc,
    double*      __restrict__ ws)
{
    const int tid = threadIdx.x;

    // ---------------- BCE blocks (no LDS use) ----------------
    if (blockIdx.x >= NBDP) {
        const int mode = mask_mode(maskarc);
        const int tot = NBATCH * L * L;
        double sph = 0.0, spt = 0.0, cnt = 0.0;
        for (int idx = (blockIdx.x - NBDP) * NT + tid; idx < tot; idx += NBCE * NT) {
            if (mask_at(maskarc, mode, idx)) {
                float x = ph[idx]; float y = (float)ph_ind[idx];
                sph += (double)(fmaxf(x, 0.0f) - x * y + log1pf(__expf(-fabsf(x))));
                x = pt[idx]; y = (float)pt_ind[idx];
                spt += (double)(fmaxf(x, 0.0f) - x * y + log1pf(__expf(-fabsf(x))));
                cnt += 1.0;
            }
        }
        for (int off = 32; off > 0; off >>= 1) {
            sph += __shfl_down(sph, off);
            spt += __shfl_down(spt, off);
            cnt += __shfl_down(cnt, off);
        }
        if ((tid & 63) == 0) {
            atomicAdd(&ws[2], sph); atomicAdd(&ws[3], spt); atomicAdd(&ws[4], cnt);
        }
        return;
    }

    // ---------------- DP blocks: 2 batches, wave-split, INDEPENDENT sync domains ----------------
    // Per batch one square SQ[half]: alpha upper [i][j] (i<=j, diag incl);
    // gamma lower [j][i] (i<j). Untouched slots hold sc.
    __shared__ __align__(16) float SQ[2][SQ_SIZE];
    __shared__ int bar[2];

    const int half = tid >> 9;          // waves 0-7 -> batch A, 8-15 -> batch B
    const int t = tid & 511;
    const int bA = blockIdx.x * 2, bB = bA + 1;
    const int bmy = half ? bB : bA;

    if (tid < 2) bar[tid] = 0;
    const int mode = mask_mode(maskspan);
    int predA = (tid < L) && mask_at(maskspan, mode, bA * L * L + tid);
    const int nA = __syncthreads_count(predA);
    int predB = (tid < L) && mask_at(maskspan, mode, bB * L * L + tid);
    const int nB = __syncthreads_count(predB);   // also publishes bar[]=0 to all waves
    const int n = half ? nB : nA;

    float* SQm = SQ[half];
    int* mybar = &bar[half];
    int tgt = 0;
    const float* lg = logits + (size_t)bmy * L * L * 2;
    const int* si = spans_ind + (size_t)bmy * L * L;

    // ---- init: sc into upper (alpha) and lower (gamma) slots ----
    for (int e = t; e < L * L; e += 512) {
        int ii = e >> 7, jj = e & (L - 1);
        if (ii <= jj && jj < n) {
            const float* p = lg + (size_t)e * 2;
            float v = lse2(p[0], p[1]);
            SQm[ii * R + jj] = v;
            if (ii < jj) SQm[jj * R + ii] = v;
        }
    }
    tgt += 8; half_barrier(mybar, tgt);

    const int sg = t >> 3, sub = t & 7;   // 64 subgroups of 8 lanes per half

    // ======== INSIDE: widths 1..n-1, per-half pacing ========
    for (int w = 1; w < n; ++w) {
        const int c = n - w;
        if (sg < c) inside_cell<16>(SQm, sg, w, sub);
        if (sg + 64 < c) inside_cell<8>(SQm, sg + 64, w, sub);   // only when w <= 63
        tgt += 8; half_barrier(mybar, tgt);
    }

    const float logZ = SQm[n - 1];   // alpha[0, n-1]

    // ======== OUTSIDE: widths n-2..1, per-half pacing ========
    for (int w = n - 2; w >= 1; --w) {
        const int c = n - w;
        if (sg < c) outside_cell<16, 8>(SQm, sg, sg + w, n, sub, true);
        if (sg + 64 < c) outside_cell<8, 16>(SQm, sg + 64, sg + 64 + w, n, sub, true);
        tgt += 8; half_barrier(mybar, tgt);
    }

    // ---- fused w=0 outside (beta_ii) + diagonal loss ----
    double local = 0.0;
#pragma unroll
    for (int pass = 0; pass < 2; ++pass) {
        const int i = sg + pass * 64;
        if (i < n) {
            float beta = (pass == 0) ? outside_cell<16, 8>(SQm, i, i, n, sub, false)
                                     : outside_cell<8, 16>(SQm, i, i, n, sub, false);
            if (sub == 0) {
                const float* p = lg + ((size_t)i * L + i) * 2;
                float lc = (si[i * L + i] == 2) ? p[1] : p[0];
                // log marg(diag) = beta_ii - logZ + l_c  (alpha_ii == sc_ii cancels)
                local += (double)fmaxf(beta - logZ + lc, LOGMIN);
            }
        }
    }

    // ---- strict-upper loss ----
    for (int e = t; e < L * L; e += 512) {
        int ii = e >> 7, jj = e & (L - 1);
        if (ii < jj && jj < n) {
            const float* p = lg + (size_t)e * 2;
            float a = p[0], cc = p[1];
            float sc = lse2(a, cc);
            float lc = (si[e] == 2) ? cc : a;
            // log marg = alpha + (gamma - sc) - logZ + l_c - sc
            float logm = SQm[ii * R + jj] + SQm[jj * R + ii] - logZ + lc - 2.0f * sc;
            local += (double)fmaxf(logm, LOGMIN);
        }
    }

    // wave reduce + one atomic per wave (waves are batch-pure)
    for (int off = 32; off > 0; off >>= 1)
        local += __shfl_down(local, off);
    if ((tid & 63) == 0) atomicAdd(&ws[0], local);
    if (t == 0) atomicAdd(&ws[1], (double)n);   // fires once per half: adds nA + nB
}

// ================= finalize =================
__global__ void finalize_kernel(const double* __restrict__ ws, float* __restrict__ out) {
    double loss_spans = -ws[0] / ws[1];
    double bce = (ws[2] + ws[3]) / ws[4];
    out[0] = (float)(0.5 * loss_spans + 0.5 * bce);
}

extern "C" void kernel_launch(void* const* d_in, const int* in_sizes, int n_in,
                              void* d_out, int out_size, void* d_ws, size_t ws_size,
                              hipStream_t stream) {
    (void)in_sizes; (void)n_in; (void)out_size; (void)ws_size;
    const float* span_logits = (const float*)d_in[0];
    const float* ph          = (const float*)d_in[1];
    const float* pt          = (const float*)d_in[2];
    /* d_in[3] = ph_arc: unused by reference */
    const int*   spans_ind   = (const int*)d_in[4];
    const int*   ph_ind      = (const int*)d_in[5];
    const int*   pt_ind      = (const int*)d_in[6];
    const void*  maskspan    = d_in[7];
    const void*  maskarc     = d_in[8];
    double* ws = (double*)d_ws;
    float* out = (float*)d_out;

    hipMemsetAsync(d_ws, 0, 5 * sizeof(double), stream);
    hipLaunchKernelGGL(tree_dp_kernel, dim3(NBDP + NBCE), dim3(NT), 0, stream,
                       span_logits, spans_ind, maskspan,
                       ph, pt, ph_ind, pt_ind, maskarc, ws);
    hipLaunchKernelGGL(finalize_kernel, dim3(1), dim3(1), 0, stream, ws, out);
}